// Round 2
// baseline (7203.139 us; speedup 1.0000x reference)
//
#include <hip/hip_runtime.h>

// LSTM fused persistent kernel for MI355X — round 2.
// 16 groups x 16 CUs; group g owns batches [16g,16g+16); CU within group owns
// 32 hidden units (128 gate-cols). Wh fp16 fragments live in VGPRs for all 512
// steps. Per-step cross-CU h exchange: per-wave relaxed sc1 (LLC) stores +
// per-wave release tags; readers do a single 64-lane tag poll (full-group
// barrier semantics) then pipelined chunk loads. No threadfence, no s_sleep,
// one __syncthreads per step.

typedef __attribute__((ext_vector_type(8))) _Float16 f16x8;
typedef __attribute__((ext_vector_type(4))) float f32x4;

#define NTHR 256
constexpr int T_LEN = 512, EMB = 1024, HID = 512, NCLS = 10;
constexpr int GSIZE = 16;   // CUs per group
constexpr int NGRP  = 16;   // groups
constexpr int BPG   = 16;   // batches per group
constexpr int UPC   = 32;   // hidden units per CU
constexpr int COLS_PC = 128;
constexpr int NKT = 16;     // K tiles of 32 (HID=512)

__device__ __forceinline__ float sigmf(float x)    { return 1.f / (1.f + __expf(-x)); }
__device__ __forceinline__ float tanhfast(float x) { return 1.f - 2.f / (__expf(2.f * x) + 1.f); }

__global__ __launch_bounds__(NTHR, 2) void lstm_fused(
    const int* __restrict__ xtok, const float* __restrict__ emb,
    const float* __restrict__ Wgx, const float* __restrict__ Wgh, const float* __restrict__ b_g,
    const float* __restrict__ Wix, const float* __restrict__ Wih, const float* __restrict__ b_i,
    const float* __restrict__ Wfx, const float* __restrict__ Wfh, const float* __restrict__ b_f,
    const float* __restrict__ Wox, const float* __restrict__ Woh, const float* __restrict__ b_o,
    const float* __restrict__ Wph, const float* __restrict__ b_p,
    float* __restrict__ out, unsigned* __restrict__ tags, _Float16* __restrict__ hbuf)
{
  const int tid  = threadIdx.x;
  const int wv   = tid >> 6;     // wave 0..3
  const int lane = tid & 63;
  const int q    = lane >> 4;    // lane quarter
  const int c    = lane & 15;
  const int wg   = blockIdx.x;
  const int grp  = wg >> 4;
  const int cu   = wg & 15;

  __shared__ __align__(16) _Float16 h_lds[2][BPG * HID];  // 2 x 16 KB, A-frag order
  __shared__ __align__(16) _Float16 hstw[4][128];         // per-wave pack staging
  __shared__ unsigned char xl[BPG][T_LEN];                // 8 KB packed tokens
  __shared__ float projl[3][COLS_PC];                     // 1.5 KB

  // ---- pack this group's tokens into LDS (u8)
  for (int idx = tid; idx < BPG * T_LEN; idx += NTHR) {
    int bl = idx >> 9, tt = idx & (T_LEN - 1);
    xl[bl][tt] = (unsigned char)xtok[(grp * BPG + bl) * T_LEN + tt];
  }

  // ---- proj[v][cc] = b_gate[j] + emb[v] . Wx[:,gate,j]   (3-row lookup table)
  if (tid < COLS_PC) {
    int cc = tid, w2 = cc >> 5, nt = (cc >> 4) & 1, c2 = cc & 15;
    int gate = nt * 2 + (c2 >> 3);
    int j = cu * UPC + w2 * 8 + (c2 & 7);
    const float* Wx = gate == 0 ? Wgx : gate == 1 ? Wix : gate == 2 ? Wfx : Wox;
    const float* bb = gate == 0 ? b_g : gate == 1 ? b_i : gate == 2 ? b_f : b_o;
    for (int v = 0; v < 3; ++v) {
      float s = bb[j];
      const float* er = emb + v * EMB;
      #pragma unroll 4
      for (int e = 0; e < EMB; ++e) s = fmaf(er[e], Wx[e * HID + j], s);
      projl[v][cc] = s;
    }
  }

  // ---- Wh B-fragments into registers (fp32 -> fp16), kept for all 512 steps.
  // Convention: (lane-quarter q, elem jj) -> k = 8q + jj, applied identically to
  // A and B, so the HW's internal k-permutation cancels.
  f16x8 Bf[2][NKT];
  {
    int g0 = c >> 3;
    int j = cu * UPC + wv * 8 + (c & 7);
    #pragma unroll
    for (int nt = 0; nt < 2; ++nt) {
      int gate = nt * 2 + g0;
      const float* W = gate == 0 ? Wgh : gate == 1 ? Wih : gate == 2 ? Wfh : Woh;
      #pragma unroll
      for (int kt = 0; kt < NKT; ++kt) {
        f16x8 tmp;
        #pragma unroll
        for (int jj = 0; jj < 8; ++jj)
          tmp[jj] = (_Float16)W[(kt * 32 + q * 8 + jj) * HID + j];
        Bf[nt][kt] = tmp;
      }
    }
  }

  float cst[4] = {0.f, 0.f, 0.f, 0.f};     // c-state, rows q*4+r
  unsigned* tg = tags + grp * 64;          // 64 per-wave tags for this group
  unsigned* hb32 = (unsigned*)hbuf;        // dword view of h buffers
  unsigned long long* hb64 = (unsigned long long*)hbuf;  // qword view
  const int gq = grp * 4096;               // group base, qwords (2 bufs x 2048)
  const int gd = grp * 8192;               // group base, dwords
  __syncthreads();

  for (int t = 0; t < T_LEN; ++t) {
    if (t > 0) {
      // ---- full-group tag barrier: all 64 per-wave tags >= t (one 64-lane load)
      const unsigned tcmp = (unsigned)t;
      for (;;) {
        unsigned tv = __hip_atomic_load(tg + lane, __ATOMIC_RELAXED, __HIP_MEMORY_SCOPE_AGENT);
        if (__all((int)(tv >= tcmp))) break;
      }
      asm volatile("" ::: "memory");
      // ---- this wave stages chunks kt = wv*4 .. wv*4+3 into LDS (A-frag order)
      const int pbase = gq + (t & 1) * 2048;
      #pragma unroll
      for (int i = 0; i < 4; ++i) {
        int kt = wv * 4 + i;
        int o = pbase + kt * 128 + lane * 2;
        unsigned long long d0 = __hip_atomic_load(hb64 + o,     __ATOMIC_RELAXED, __HIP_MEMORY_SCOPE_AGENT);
        unsigned long long d1 = __hip_atomic_load(hb64 + o + 1, __ATOMIC_RELAXED, __HIP_MEMORY_SCOPE_AGENT);
        unsigned long long* dl = (unsigned long long*)&h_lds[t & 1][kt * 512 + lane * 8];
        dl[0] = d0; dl[1] = d1;
      }
    }
    __syncthreads();

    // ---- gates tile: 16 batches x 32 cols per wave (2 n-tiles), K=512
    f32x4 acc0 = {0.f, 0.f, 0.f, 0.f}, acc1 = {0.f, 0.f, 0.f, 0.f};
    if (t > 0) {
      const _Float16* hp = h_lds[t & 1];
      #pragma unroll
      for (int kt = 0; kt < NKT; ++kt) {
        f16x8 a = *(const f16x8*)(hp + kt * 512 + lane * 8);
        acc0 = __builtin_amdgcn_mfma_f32_16x16x32_f16(a, Bf[0][kt], acc0, 0, 0, 0);
        acc1 = __builtin_amdgcn_mfma_f32_16x16x32_f16(a, Bf[1][kt], acc1, 0, 0, 0);
      }
    }

    // ---- nonlinearity + state update. C/D layout: col=lane&15, row=4q+reg.
    bool lo = (c < 8);
    #pragma unroll
    for (int r = 0; r < 4; ++r) {
      int bl = q * 4 + r;                     // batch row in tile
      int v = xl[bl][t];
      float p0 = acc0[r] + projl[v][wv * 32 + c];
      float p1 = acc1[r] + projl[v][wv * 32 + 16 + c];
      float p0x = __shfl_xor(p0, 8);
      float p1x = __shfl_xor(p1, 8);
      float gg = lo ? p0  : p0x;
      float ii = lo ? p0x : p0;
      float ff = lo ? p1  : p1x;
      float oo = lo ? p1x : p1;
      gg = tanhfast(gg); ii = sigmf(ii); ff = sigmf(ff); oo = sigmf(oo);
      float cn = fmaf(cst[r], ff, gg * ii);
      cst[r] = cn;
      float hv = tanhfast(cn) * oo;
      // h(bl, unit wv*8+(c&7)) -> wave slice layout [bl][jj]
      if (lo) hstw[wv][bl * 8 + c] = (_Float16)hv;
    }

    // ---- publish this wave's 256B slice + release tag (per-wave vmcnt ordering)
    unsigned pub = ((const unsigned*)&hstw[wv][0])[lane];
    int po = gd + ((t + 1) & 1) * 4096 + cu * 256 + wv * 64 + lane;
    __hip_atomic_store(hb32 + po, pub, __ATOMIC_RELAXED, __HIP_MEMORY_SCOPE_AGENT);
    if (lane == 0)
      __hip_atomic_store(tg + cu * 4 + wv, (unsigned)(t + 1), __ATOMIC_RELEASE, __HIP_MEMORY_SCOPE_AGENT);
  }

  // ---- epilogue: p = h_T @ W_ph + b_p ; log_softmax. WG cu handles batch grp*16+cu.
  // h_T is in buffer parity (T_LEN)&1 == 0.
  if (wv == 0) {
    for (;;) {
      unsigned tv = __hip_atomic_load(tg + lane, __ATOMIC_RELAXED, __HIP_MEMORY_SCOPE_AGENT);
      if (__all((int)(tv >= (unsigned)T_LEN))) break;
    }
    asm volatile("" ::: "memory");
    float pc[NCLS];
    #pragma unroll
    for (int k2 = 0; k2 < NCLS; ++k2) pc[k2] = 0.f;
    int kt = lane >> 2, qa = lane & 3;        // each lane: 8 consecutive j
    const unsigned long long* hs = hb64 + gq + (kt * 64 + qa * 16 + cu) * 2;
    unsigned long long d0 = __hip_atomic_load(hs,     __ATOMIC_RELAXED, __HIP_MEMORY_SCOPE_AGENT);
    unsigned long long d1 = __hip_atomic_load(hs + 1, __ATOMIC_RELAXED, __HIP_MEMORY_SCOPE_AGENT);
    _Float16 hh[8];
    __builtin_memcpy(&hh[0], &d0, 8);
    __builtin_memcpy(&hh[4], &d1, 8);
    int jbase = kt * 32 + qa * 8;
    #pragma unroll
    for (int jj = 0; jj < 8; ++jj) {
      float hv = (float)hh[jj];
      const float* wr = Wph + (jbase + jj) * NCLS;
      #pragma unroll
      for (int k2 = 0; k2 < NCLS; ++k2) pc[k2] = fmaf(hv, wr[k2], pc[k2]);
    }
    #pragma unroll
    for (int off = 32; off > 0; off >>= 1) {
      #pragma unroll
      for (int k2 = 0; k2 < NCLS; ++k2) pc[k2] += __shfl_down(pc[k2], off);
    }
    if (lane == 0) {
      float mx = -1e30f;
      #pragma unroll
      for (int k2 = 0; k2 < NCLS; ++k2) { pc[k2] += b_p[k2]; mx = fmaxf(mx, pc[k2]); }
      float se = 0.f;
      #pragma unroll
      for (int k2 = 0; k2 < NCLS; ++k2) se += __expf(pc[k2] - mx);
      float ls = mx + __logf(se);
      int b = grp * BPG + cu;
      #pragma unroll
      for (int k2 = 0; k2 < NCLS; ++k2) out[b * NCLS + k2] = pc[k2] - ls;
    }
  }
}

extern "C" void kernel_launch(void* const* d_in, const int* in_sizes, int n_in,
                              void* d_out, int out_size, void* d_ws, size_t ws_size,
                              hipStream_t stream) {
  (void)in_sizes; (void)n_in; (void)out_size; (void)ws_size;
  const int*   x   = (const int*)d_in[0];
  const float* emb = (const float*)d_in[1];
  const float* Wgx = (const float*)d_in[2];
  const float* Wgh = (const float*)d_in[3];
  const float* bg  = (const float*)d_in[4];
  const float* Wix = (const float*)d_in[5];
  const float* Wih = (const float*)d_in[6];
  const float* bi  = (const float*)d_in[7];
  const float* Wfx = (const float*)d_in[8];
  const float* Wfh = (const float*)d_in[9];
  const float* bfv = (const float*)d_in[10];
  const float* Wox = (const float*)d_in[11];
  const float* Woh = (const float*)d_in[12];
  const float* bo  = (const float*)d_in[13];
  const float* Wph = (const float*)d_in[14];
  const float* bp  = (const float*)d_in[15];
  float* out = (float*)d_out;

  unsigned* tags = (unsigned*)d_ws;                        // 4 KB, zeroed per launch
  _Float16* hbuf = (_Float16*)((char*)d_ws + 8192);        // 512 KB h double-buffer

  hipMemsetAsync(d_ws, 0, 4096, stream);                   // reset tags
  lstm_fused<<<dim3(NGRP * GSIZE), dim3(NTHR), 0, stream>>>(
      x, emb, Wgx, Wgh, bg, Wix, Wih, bi, Wfx, Wfh, bfv,
      Wox, Woh, bo, Wph, bp, out, tags, hbuf);
}

// Round 4
// 6408.492 us; speedup vs baseline: 1.1240x; 1.1240x over previous
//
#include <hip/hip_runtime.h>

// LSTM fused persistent kernel for MI355X — round 4 (R3 + proj-reduction fix).
// 16 groups x 16 CUs; CU owns 32 hidden units (128 gate-cols), Wh fp16 in VGPRs.
// Cross-CU h exchange per step via LLC (sc1) with NARROW dataflow polling:
// wave wv stages chunks 4wv..4wv+3 and polls ONLY their 16 producer tags
// (one 64B line, 16 pollers per line). Lag bound D=2 (poll transitivity) ->
// triple-buffered global h, double-buffered LDS, one __syncthreads per step.

typedef __attribute__((ext_vector_type(8))) _Float16 f16x8;
typedef __attribute__((ext_vector_type(4))) float f32x4;

#define NTHR 256
constexpr int T_LEN = 512, EMB = 1024, HID = 512, NCLS = 10;
constexpr int GSIZE = 16;   // CUs per group
constexpr int NGRP  = 16;   // groups
constexpr int BPG   = 16;   // batches per group
constexpr int UPC   = 32;   // hidden units per CU
constexpr int COLS_PC = 128;
constexpr int NKT = 16;     // K tiles of 32 (HID=512)

__device__ __forceinline__ float sigmf(float x)    { return 1.f / (1.f + __expf(-x)); }
__device__ __forceinline__ float tanhfast(float x) { return 1.f - 2.f / (__expf(2.f * x) + 1.f); }

__global__ __launch_bounds__(NTHR, 1) void lstm_fused(
    const int* __restrict__ xtok, const float* __restrict__ emb,
    const float* __restrict__ Wgx, const float* __restrict__ Wgh, const float* __restrict__ b_g,
    const float* __restrict__ Wix, const float* __restrict__ Wih, const float* __restrict__ b_i,
    const float* __restrict__ Wfx, const float* __restrict__ Wfh, const float* __restrict__ b_f,
    const float* __restrict__ Wox, const float* __restrict__ Woh, const float* __restrict__ b_o,
    const float* __restrict__ Wph, const float* __restrict__ b_p,
    float* __restrict__ out, unsigned* __restrict__ tags, _Float16* __restrict__ hbuf)
{
  const int tid  = threadIdx.x;
  const int wv   = tid >> 6;     // wave 0..3
  const int lane = tid & 63;
  const int q    = lane >> 4;    // lane quarter
  const int c    = lane & 15;
  const int wg   = blockIdx.x;
  const int grp  = wg >> 4;
  const int cu   = wg & 15;

  __shared__ __align__(16) _Float16 h_lds[2][BPG * HID];  // 2 x 16 KB, chunk-major
  __shared__ __align__(16) _Float16 hstw[4][128];         // per-wave pack staging
  __shared__ unsigned char xl[BPG][T_LEN];                // 8 KB packed tokens
  __shared__ float projl[3][COLS_PC];                     // 1.5 KB
  __shared__ float projp[3][COLS_PC];                     // 1.5 KB partials

  // ---- pack this group's tokens into LDS (u8)
  for (int idx = tid; idx < BPG * T_LEN; idx += NTHR) {
    int bl = idx >> 9, tt = idx & (T_LEN - 1);
    xl[bl][tt] = (unsigned char)xtok[(grp * BPG + bl) * T_LEN + tt];
  }

  // ---- proj[v][cc] = b_gate[j] + emb[v] . Wx[:,gate,j], split over 2 halves of e
  {
    int cc = tid & 127, half = tid >> 7;
    int w2 = cc >> 5, nt = (cc >> 4) & 1, c2 = cc & 15;
    int gate = nt * 2 + (c2 >> 3);
    int j = cu * UPC + w2 * 8 + (c2 & 7);
    const float* Wx = gate == 0 ? Wgx : gate == 1 ? Wix : gate == 2 ? Wfx : Wox;
    const float* bb = gate == 0 ? b_g : gate == 1 ? b_i : gate == 2 ? b_f : b_o;
    int e0 = half * (EMB / 2);
    for (int v = 0; v < 3; ++v) {
      float s = half ? 0.f : bb[j];
      const float* er = emb + v * EMB + e0;
      const float* wp = Wx + e0 * HID + j;
      #pragma unroll 4
      for (int e = 0; e < EMB / 2; ++e) s = fmaf(er[e], wp[e * HID], s);
      (half ? projp : projl)[v][cc] = s;
    }
  }
  __syncthreads();
  for (int idx = tid; idx < 3 * COLS_PC; idx += NTHR) {   // BUGFIX: cover v=2
    int v = idx >> 7, cc = idx & 127;
    projl[v][cc] += projp[v][cc];
  }

  // ---- Wh B-fragments into registers (fp32 -> fp16), kept for all 512 steps.
  // (q, jj) -> k = 8q + jj, applied identically to A and B (HW perm cancels).
  f16x8 Bf[2][NKT];
  {
    int g0 = c >> 3;
    int j = cu * UPC + wv * 8 + (c & 7);
    #pragma unroll
    for (int nt = 0; nt < 2; ++nt) {
      int gate = nt * 2 + g0;
      const float* W = gate == 0 ? Wgh : gate == 1 ? Wih : gate == 2 ? Wfh : Woh;
      #pragma unroll
      for (int kt = 0; kt < NKT; ++kt) {
        f16x8 tmp;
        #pragma unroll
        for (int jj = 0; jj < 8; ++jj)
          tmp[jj] = (_Float16)W[(kt * 32 + q * 8 + jj) * HID + j];
        Bf[nt][kt] = tmp;
      }
    }
  }

  float cst[4] = {0.f, 0.f, 0.f, 0.f};     // c-state, rows q*4+r
  unsigned* tg = tags + grp * 64;          // 64 per-wave tags; line wv = its producers
  unsigned* hb32 = (unsigned*)hbuf;
  unsigned long long* hb64 = (unsigned long long*)hbuf;
  const int gq3 = grp * 3 * 2048;          // group base, qwords (3 bufs x 2048)
  const int gd3 = grp * 3 * 4096;          // group base, dwords
  int bufr = 0;                            // == t % 3
  __syncthreads();

  for (int t = 0; t < T_LEN; ++t) {
    const int pl = t & 1;
    if (t > 0) {
      // ---- narrow poll: my 16 producers (CUs 4wv..4wv+3, all waves) >= t.
      // tag>=t implies (transitively) all group waves >= t-1, so the buffer
      // we will overwrite at distance 3 has been fully consumed, and the
      // chunks we read were fully published.
      const unsigned tcmp = (unsigned)t;
      const unsigned* myline = tg + wv * 16;
      for (;;) {
        unsigned tv = __hip_atomic_load(myline + (lane & 15), __ATOMIC_RELAXED, __HIP_MEMORY_SCOPE_AGENT);
        if (__all((int)(tv >= tcmp))) break;
      }
      asm volatile("" ::: "memory");
      // ---- stage chunks kt = wv*4 .. wv*4+3 into LDS (chunk layout == A-frag)
      const int pbase = gq3 + bufr * 2048;
      #pragma unroll
      for (int i = 0; i < 4; ++i) {
        int kt = wv * 4 + i;
        int o = pbase + kt * 128 + lane * 2;
        unsigned long long d0 = __hip_atomic_load(hb64 + o,     __ATOMIC_RELAXED, __HIP_MEMORY_SCOPE_AGENT);
        unsigned long long d1 = __hip_atomic_load(hb64 + o + 1, __ATOMIC_RELAXED, __HIP_MEMORY_SCOPE_AGENT);
        unsigned long long* dl = (unsigned long long*)&h_lds[pl][kt * 512 + lane * 8];
        dl[0] = d0; dl[1] = d1;
      }
    }
    __syncthreads();

    // ---- gates tile: 16 batches x 32 cols per wave (2 n-tiles), K=512
    f32x4 acc0 = {0.f, 0.f, 0.f, 0.f}, acc1 = {0.f, 0.f, 0.f, 0.f};
    if (t > 0) {
      const _Float16* hp = h_lds[pl];
      #pragma unroll
      for (int kt = 0; kt < NKT; ++kt) {
        f16x8 a = *(const f16x8*)(hp + kt * 512 + lane * 8);
        acc0 = __builtin_amdgcn_mfma_f32_16x16x32_f16(a, Bf[0][kt], acc0, 0, 0, 0);
        acc1 = __builtin_amdgcn_mfma_f32_16x16x32_f16(a, Bf[1][kt], acc1, 0, 0, 0);
      }
    }

    // ---- nonlinearity + state update. C/D layout: col=lane&15, row=4q+reg.
    bool lo = (c < 8);
    #pragma unroll
    for (int r = 0; r < 4; ++r) {
      int bl = q * 4 + r;                     // batch row in tile
      int v = xl[bl][t];
      float p0 = acc0[r] + projl[v][wv * 32 + c];
      float p1 = acc1[r] + projl[v][wv * 32 + 16 + c];
      float p0x = __shfl_xor(p0, 8);
      float p1x = __shfl_xor(p1, 8);
      float gg = lo ? p0  : p0x;
      float ii = lo ? p0x : p0;
      float ff = lo ? p1  : p1x;
      float oo = lo ? p1x : p1;
      gg = tanhfast(gg); ii = sigmf(ii); ff = sigmf(ff); oo = sigmf(oo);
      float cn = fmaf(cst[r], ff, gg * ii);
      cst[r] = cn;
      float hv = tanhfast(cn) * oo;
      if (lo) hstw[wv][bl * 8 + c] = (_Float16)hv;   // same-wave staging (no barrier)
    }

    // ---- publish this wave's 256B slice into buffer (t+1)%3 + release tag
    int bufw = bufr + 1; if (bufw == 3) bufw = 0;
    unsigned pub = ((const unsigned*)&hstw[wv][0])[lane];
    int po = gd3 + bufw * 4096 + cu * 256 + wv * 64 + lane;
    __hip_atomic_store(hb32 + po, pub, __ATOMIC_RELAXED, __HIP_MEMORY_SCOPE_AGENT);
    if (lane == 0)
      __hip_atomic_store(tg + cu * 4 + wv, (unsigned)(t + 1), __ATOMIC_RELEASE, __HIP_MEMORY_SCOPE_AGENT);
    bufr = bufw;
  }

  // ---- epilogue (R2-proven form): wave0 polls all 64 tags, then computes
  // p = h_T @ W_ph + b_p ; log_softmax for batch grp*16+cu. h_512 in buffer 2.
  if (wv == 0) {
    for (;;) {
      unsigned tv = __hip_atomic_load(tg + lane, __ATOMIC_RELAXED, __HIP_MEMORY_SCOPE_AGENT);
      if (__all((int)(tv >= (unsigned)T_LEN))) break;
    }
    asm volatile("" ::: "memory");
    float pc[NCLS];
    #pragma unroll
    for (int k2 = 0; k2 < NCLS; ++k2) pc[k2] = 0.f;
    int kt = lane >> 2, qa = lane & 3;        // each lane: 8 consecutive j
    const unsigned long long* hs = hb64 + gq3 + 2 * 2048 + (kt * 64 + qa * 16 + cu) * 2;
    unsigned long long d0 = __hip_atomic_load(hs,     __ATOMIC_RELAXED, __HIP_MEMORY_SCOPE_AGENT);
    unsigned long long d1 = __hip_atomic_load(hs + 1, __ATOMIC_RELAXED, __HIP_MEMORY_SCOPE_AGENT);
    _Float16 hh[8];
    __builtin_memcpy(&hh[0], &d0, 8);
    __builtin_memcpy(&hh[4], &d1, 8);
    int jbase = kt * 32 + qa * 8;
    #pragma unroll
    for (int jj = 0; jj < 8; ++jj) {
      float hv = (float)hh[jj];
      const float* wr = Wph + (jbase + jj) * NCLS;
      #pragma unroll
      for (int k2 = 0; k2 < NCLS; ++k2) pc[k2] = fmaf(hv, wr[k2], pc[k2]);
    }
    #pragma unroll
    for (int off = 32; off > 0; off >>= 1) {
      #pragma unroll
      for (int k2 = 0; k2 < NCLS; ++k2) pc[k2] += __shfl_down(pc[k2], off);
    }
    if (lane == 0) {
      float mx = -1e30f;
      #pragma unroll
      for (int k2 = 0; k2 < NCLS; ++k2) { pc[k2] += b_p[k2]; mx = fmaxf(mx, pc[k2]); }
      float se = 0.f;
      #pragma unroll
      for (int k2 = 0; k2 < NCLS; ++k2) se += __expf(pc[k2] - mx);
      float ls = mx + __logf(se);
      int b = grp * BPG + cu;
      #pragma unroll
      for (int k2 = 0; k2 < NCLS; ++k2) out[b * NCLS + k2] = pc[k2] - ls;
    }
  }
}

extern "C" void kernel_launch(void* const* d_in, const int* in_sizes, int n_in,
                              void* d_out, int out_size, void* d_ws, size_t ws_size,
                              hipStream_t stream) {
  (void)in_sizes; (void)n_in; (void)out_size; (void)ws_size;
  const int*   x   = (const int*)d_in[0];
  const float* emb = (const float*)d_in[1];
  const float* Wgx = (const float*)d_in[2];
  const float* Wgh = (const float*)d_in[3];
  const float* bg  = (const float*)d_in[4];
  const float* Wix = (const float*)d_in[5];
  const float* Wih = (const float*)d_in[6];
  const float* bi  = (const float*)d_in[7];
  const float* Wfx = (const float*)d_in[8];
  const float* Wfh = (const float*)d_in[9];
  const float* bfv = (const float*)d_in[10];
  const float* Wox = (const float*)d_in[11];
  const float* Woh = (const float*)d_in[12];
  const float* bo  = (const float*)d_in[13];
  const float* Wph = (const float*)d_in[14];
  const float* bp  = (const float*)d_in[15];
  float* out = (float*)d_out;

  unsigned* tags = (unsigned*)d_ws;                        // 4 KB, zeroed per launch
  _Float16* hbuf = (_Float16*)((char*)d_ws + 8192);        // 768 KB h triple-buffer

  hipMemsetAsync(d_ws, 0, 4096, stream);                   // reset tags
  lstm_fused<<<dim3(NGRP * GSIZE), dim3(NTHR), 0, stream>>>(
      x, emb, Wgx, Wgh, bg, Wix, Wih, bi, Wfx, Wfh, bfv,
      Wox, Woh, bo, Wph, bp, out, tags, hbuf);
}